// Round 1
// baseline (136.337 us; speedup 1.0000x reference)
//
#include <hip/hip_runtime.h>

#define NATOM 96
#define EDIM  16
#define HDIM  64
#define BN    (32 * 96)   // B*N = 3072 atoms

// ---------------------------------------------------------------------------
// Kernel 1: per-atom precompute  u_a = x_a@W1[0:65]+b1,  v_a = x_a@W1[65:130]
// x_a = [h_a (64), q_a (1)]
// ---------------------------------------------------------------------------
__global__ void uv_kernel(const float* __restrict__ h,
                          const float* __restrict__ q,
                          const float* __restrict__ W1,
                          const float* __restrict__ b1,
                          float* __restrict__ u,
                          float* __restrict__ v) {
    int id = blockIdx.x * 256 + threadIdx.x;
    if (id >= BN * 32) return;
    int a = id >> 5;
    int m = id & 31;
    const float* ha = h + (size_t)a * HDIM;
    float qa = q[a];
    float su = b1[m];
    float sv = 0.f;
#pragma unroll 8
    for (int f = 0; f < HDIM; ++f) {
        float hf = ha[f];
        su = fmaf(hf, W1[f * 32 + m], su);
        sv = fmaf(hf, W1[(65 + f) * 32 + m], sv);
    }
    su = fmaf(qa, W1[64 * 32 + m], su);
    sv = fmaf(qa, W1[129 * 32 + m], sv);
    u[id] = su;
    v[id] = sv;
}

// ---------------------------------------------------------------------------
// Kernel 2: one block per (b,i) row; thread j handles edge (i,j).
//   t      = e_ij @ W1c                  (shared between directions)
//   z1_ij  = relu(u_i + v_j + t)   z1_ji = relu(u_j + v_i + t)
//   z2_*   = relu(z1_* @ W2 + b2)
//   elec_* = relu(z2_*) . W3             (b3 cancels in the difference)
//   val    = (elec_ij - elec_ji) * mask;  q_out[b,i] = q_in[b,i] + sum_j val
// ---------------------------------------------------------------------------
__global__ __launch_bounds__(128) void edge_kernel(
    const float* __restrict__ e,
    const float* __restrict__ mask,
    const float* __restrict__ qin,
    const float* __restrict__ W1,
    const float* __restrict__ W2,
    const float* __restrict__ b2,
    const float* __restrict__ W3,
    const float* __restrict__ u,
    const float* __restrict__ v,
    float* __restrict__ qout)
{
    __shared__ __attribute__((aligned(16))) float sW1c[512];   // 16 x 32
    __shared__ __attribute__((aligned(16))) float sW2[1024];   // 32 x 32
    __shared__ __attribute__((aligned(16))) float sW3[32];
    __shared__ __attribute__((aligned(16))) float sB2[32];
    __shared__ __attribute__((aligned(16))) float sUi[32];
    __shared__ __attribute__((aligned(16))) float sVi[32];
    __shared__ float sRed[2];

    const int bi  = blockIdx.x;        // b*96 + i
    const int tid = threadIdx.x;
    const int b   = bi / NATOM;

    for (int idx = tid; idx < 512; idx += 128)  sW1c[idx] = W1[130 * 32 + idx];
    for (int idx = tid; idx < 1024; idx += 128) sW2[idx]  = W2[idx];
    if (tid < 32) {
        sW3[tid] = W3[tid];
        sB2[tid] = b2[tid];
        sUi[tid] = u[bi * 32 + tid];
        sVi[tid] = v[bi * 32 + tid];
    }
    __syncthreads();

    float val = 0.f;
    if (tid < NATOM) {
        const int j = tid;

        // ---- load e_ij (16 floats) ----
        const float4* e4 = (const float4*)(e + ((size_t)bi * NATOM + j) * EDIM);
        float4 e0 = e4[0], e1 = e4[1], e2 = e4[2], e3 = e4[3];
        float ef[16];
        ef[0]  = e0.x; ef[1]  = e0.y; ef[2]  = e0.z; ef[3]  = e0.w;
        ef[4]  = e1.x; ef[5]  = e1.y; ef[6]  = e1.z; ef[7]  = e1.w;
        ef[8]  = e2.x; ef[9]  = e2.y; ef[10] = e2.z; ef[11] = e2.w;
        ef[12] = e3.x; ef[13] = e3.y; ef[14] = e3.z; ef[15] = e3.w;

        // ---- t = e @ W1c ----
        float t[32];
#pragma unroll
        for (int m = 0; m < 32; ++m) t[m] = 0.f;
#pragma unroll
        for (int f = 0; f < 16; ++f) {
            float ev = ef[f];
            const float4* wr = (const float4*)(sW1c + f * 32);
#pragma unroll
            for (int m4 = 0; m4 < 8; ++m4) {
                float4 w = wr[m4];
                t[4 * m4 + 0] = fmaf(ev, w.x, t[4 * m4 + 0]);
                t[4 * m4 + 1] = fmaf(ev, w.y, t[4 * m4 + 1]);
                t[4 * m4 + 2] = fmaf(ev, w.z, t[4 * m4 + 2]);
                t[4 * m4 + 3] = fmaf(ev, w.w, t[4 * m4 + 3]);
            }
        }

        // ---- z1 for both directions ----
        const float4* uj4 = (const float4*)(u + ((size_t)(b * NATOM + j)) * 32);
        const float4* vj4 = (const float4*)(v + ((size_t)(b * NATOM + j)) * 32);
        float z1ij[32], z1ji[32];
#pragma unroll
        for (int m4 = 0; m4 < 8; ++m4) {
            float4 uj = uj4[m4];
            float4 vj = vj4[m4];
            float4 ui = ((const float4*)sUi)[m4];
            float4 vi = ((const float4*)sVi)[m4];
            z1ij[4 * m4 + 0] = fmaxf(ui.x + vj.x + t[4 * m4 + 0], 0.f);
            z1ij[4 * m4 + 1] = fmaxf(ui.y + vj.y + t[4 * m4 + 1], 0.f);
            z1ij[4 * m4 + 2] = fmaxf(ui.z + vj.z + t[4 * m4 + 2], 0.f);
            z1ij[4 * m4 + 3] = fmaxf(ui.w + vj.w + t[4 * m4 + 3], 0.f);
            z1ji[4 * m4 + 0] = fmaxf(uj.x + vi.x + t[4 * m4 + 0], 0.f);
            z1ji[4 * m4 + 1] = fmaxf(uj.y + vi.y + t[4 * m4 + 1], 0.f);
            z1ji[4 * m4 + 2] = fmaxf(uj.z + vi.z + t[4 * m4 + 2], 0.f);
            z1ji[4 * m4 + 3] = fmaxf(uj.w + vi.w + t[4 * m4 + 3], 0.f);
        }

        // ---- layer 2: z1 @ W2 + b2 (both directions share each W2 read) ----
        float aij[32], aji[32];
#pragma unroll
        for (int m = 0; m < 32; ++m) { aij[m] = sB2[m]; aji[m] = sB2[m]; }
#pragma unroll
        for (int k = 0; k < 32; ++k) {
            float zij = z1ij[k];
            float zji = z1ji[k];
            const float4* wr = (const float4*)(sW2 + k * 32);
#pragma unroll
            for (int m4 = 0; m4 < 8; ++m4) {
                float4 w = wr[m4];
                aij[4 * m4 + 0] = fmaf(zij, w.x, aij[4 * m4 + 0]);
                aij[4 * m4 + 1] = fmaf(zij, w.y, aij[4 * m4 + 1]);
                aij[4 * m4 + 2] = fmaf(zij, w.z, aij[4 * m4 + 2]);
                aij[4 * m4 + 3] = fmaf(zij, w.w, aij[4 * m4 + 3]);
                aji[4 * m4 + 0] = fmaf(zji, w.x, aji[4 * m4 + 0]);
                aji[4 * m4 + 1] = fmaf(zji, w.y, aji[4 * m4 + 1]);
                aji[4 * m4 + 2] = fmaf(zji, w.z, aji[4 * m4 + 2]);
                aji[4 * m4 + 3] = fmaf(zji, w.w, aji[4 * m4 + 3]);
            }
        }

        // ---- layer 3: relu then dot with W3 (b3 cancels) ----
        float sij = 0.f, sji = 0.f;
#pragma unroll
        for (int m = 0; m < 32; ++m) {
            sij = fmaf(fmaxf(aij[m], 0.f), sW3[m], sij);
            sji = fmaf(fmaxf(aji[m], 0.f), sW3[m], sji);
        }

        val = (sij - sji) * mask[(size_t)bi * NATOM + j];
    }

    // ---- block reduction over j (2 waves of 64) ----
#pragma unroll
    for (int off = 32; off > 0; off >>= 1) val += __shfl_xor(val, off);
    if ((tid & 63) == 0) sRed[tid >> 6] = val;
    __syncthreads();
    if (tid == 0) qout[bi] = qin[bi] + sRed[0] + sRed[1];
}

// ---------------------------------------------------------------------------
extern "C" void kernel_launch(void* const* d_in, const int* in_sizes, int n_in,
                              void* d_out, int out_size, void* d_ws, size_t ws_size,
                              hipStream_t stream) {
    const float* h    = (const float*)d_in[0];
    const float* e    = (const float*)d_in[1];
    const float* q    = (const float*)d_in[2];
    const float* mask = (const float*)d_in[3];
    const float* W1   = (const float*)d_in[4];
    const float* b1   = (const float*)d_in[5];
    const float* W2   = (const float*)d_in[6];
    const float* b2   = (const float*)d_in[7];
    const float* W3   = (const float*)d_in[8];
    // d_in[9] = b3: cancels exactly in (elec_ij - elec_ji); unused.

    float* u = (float*)d_ws;               // BN*32 floats
    float* v = u + BN * 32;                // BN*32 floats
    float* qout = (float*)d_out;           // BN floats

    uv_kernel<<<(BN * 32 + 255) / 256, 256, 0, stream>>>(h, q, W1, b1, u, v);
    edge_kernel<<<BN, 128, 0, stream>>>(e, mask, q, W1, W2, b2, W3, u, v, qout);
}

// Round 5
// 130.716 us; speedup vs baseline: 1.0430x; 1.0430x over previous
//
#include <hip/hip_runtime.h>

#define NATOM 96
#define EDIM  16
#define HDIM  64
#define BN    (32 * 96)   // B*N = 3072 atoms

// ---------------------------------------------------------------------------
// Kernel 1: per-atom precompute  u_a = x_a@W1[0:65]+b1,  v_a = x_a@W1[65:130]
// x_a = [h_a (64), q_a (1)]
// ---------------------------------------------------------------------------
__global__ void uv_kernel(const float* __restrict__ h,
                          const float* __restrict__ q,
                          const float* __restrict__ W1,
                          const float* __restrict__ b1,
                          float* __restrict__ u,
                          float* __restrict__ v) {
    int id = blockIdx.x * 256 + threadIdx.x;
    if (id >= BN * 32) return;
    int a = id >> 5;
    int m = id & 31;
    const float* ha = h + (size_t)a * HDIM;
    float qa = q[a];
    float su = b1[m];
    float sv = 0.f;
#pragma unroll 8
    for (int f = 0; f < HDIM; ++f) {
        float hf = ha[f];
        su = fmaf(hf, W1[f * 32 + m], su);
        sv = fmaf(hf, W1[(65 + f) * 32 + m], sv);
    }
    su = fmaf(qa, W1[64 * 32 + m], su);
    sv = fmaf(qa, W1[129 * 32 + m], sv);
    u[id] = su;
    v[id] = sv;
}

// ---------------------------------------------------------------------------
// Kernel 2: block = 384 threads = 4 rows (b,i) x 96 edges j. Every thread
// owns one edge; both MLP directions computed sequentially sharing
// t = e_ij @ W1c. All weights (W1c, W2, b2, W3) are indexed with
// wave-uniform compile-time offsets from kernel-arg pointers -> scalar
// loads (SGPR operands): zero LDS/VMEM vector cost per FMA.
// ---------------------------------------------------------------------------
__global__ __launch_bounds__(384) void edge_kernel(
    const float* __restrict__ e,
    const float* __restrict__ mask,
    const float* __restrict__ qin,
    const float* __restrict__ W1,
    const float* __restrict__ W2,
    const float* __restrict__ b2,
    const float* __restrict__ W3,
    const float* __restrict__ u,
    const float* __restrict__ v,
    float* __restrict__ qout)
{
    __shared__ float sVal[4][NATOM];

    const int tid = threadIdx.x;
    const int r   = tid / NATOM;          // 0..3: row within block
    const int j   = tid - r * NATOM;      // 0..95: edge target atom
    const int bi0 = blockIdx.x * 4;       // first (b,i) row of this block
    const int bi  = bi0 + r;
    const int b   = bi / NATOM;           // molecule (4-row group never crosses b)

    const float* __restrict__ W1c = W1 + 130 * 32;   // e-part of W1, 16x32

    // ---- load e_ij (16 floats, coalesced: thread j consecutive) ----
    const float4* e4 = (const float4*)(e + ((size_t)bi * NATOM + j) * EDIM);
    float4 e0 = e4[0], e1 = e4[1], e2 = e4[2], e3 = e4[3];
    float ef[16];
    ef[0]  = e0.x; ef[1]  = e0.y; ef[2]  = e0.z; ef[3]  = e0.w;
    ef[4]  = e1.x; ef[5]  = e1.y; ef[6]  = e1.z; ef[7]  = e1.w;
    ef[8]  = e2.x; ef[9]  = e2.y; ef[10] = e2.z; ef[11] = e2.w;
    ef[12] = e3.x; ef[13] = e3.y; ef[14] = e3.z; ef[15] = e3.w;

    // ---- t = e @ W1c  (W1c via scalar loads) ----
    float t[32];
#pragma unroll
    for (int m = 0; m < 32; ++m) t[m] = 0.f;
#pragma unroll
    for (int f = 0; f < EDIM; ++f) {
        float ev = ef[f];
#pragma unroll
        for (int m = 0; m < 32; ++m)
            t[m] = fmaf(ev, W1c[f * 32 + m], t[m]);
    }

    const float4* ui4 = (const float4*)(u + (size_t)bi * 32);
    const float4* vi4 = (const float4*)(v + (size_t)bi * 32);
    const float4* uj4 = (const float4*)(u + ((size_t)(b * NATOM + j)) * 32);
    const float4* vj4 = (const float4*)(v + ((size_t)(b * NATOM + j)) * 32);

    // ================= direction ij: z1 = relu(u_i + v_j + t) ==============
    float z1[32];
#pragma unroll
    for (int m4 = 0; m4 < 8; ++m4) {
        float4 a = ui4[m4];
        float4 c = vj4[m4];
        z1[4 * m4 + 0] = fmaxf(a.x + c.x + t[4 * m4 + 0], 0.f);
        z1[4 * m4 + 1] = fmaxf(a.y + c.y + t[4 * m4 + 1], 0.f);
        z1[4 * m4 + 2] = fmaxf(a.z + c.z + t[4 * m4 + 2], 0.f);
        z1[4 * m4 + 3] = fmaxf(a.w + c.w + t[4 * m4 + 3], 0.f);
    }
    float acc[32];
#pragma unroll
    for (int m = 0; m < 32; ++m) acc[m] = b2[m];
#pragma unroll
    for (int k = 0; k < 32; ++k) {
        float z = z1[k];
#pragma unroll
        for (int m = 0; m < 32; ++m)
            acc[m] = fmaf(z, W2[k * 32 + m], acc[m]);
    }
    float sij = 0.f;
#pragma unroll
    for (int m = 0; m < 32; ++m)
        sij = fmaf(fmaxf(acc[m], 0.f), W3[m], sij);

    // ================= direction ji: z1 = relu(u_j + v_i + t) ==============
#pragma unroll
    for (int m4 = 0; m4 < 8; ++m4) {
        float4 a = uj4[m4];
        float4 c = vi4[m4];
        z1[4 * m4 + 0] = fmaxf(a.x + c.x + t[4 * m4 + 0], 0.f);
        z1[4 * m4 + 1] = fmaxf(a.y + c.y + t[4 * m4 + 1], 0.f);
        z1[4 * m4 + 2] = fmaxf(a.z + c.z + t[4 * m4 + 2], 0.f);
        z1[4 * m4 + 3] = fmaxf(a.w + c.w + t[4 * m4 + 3], 0.f);
    }
#pragma unroll
    for (int m = 0; m < 32; ++m) acc[m] = b2[m];
#pragma unroll
    for (int k = 0; k < 32; ++k) {
        float z = z1[k];
#pragma unroll
        for (int m = 0; m < 32; ++m)
            acc[m] = fmaf(z, W2[k * 32 + m], acc[m]);
    }
    float sji = 0.f;
#pragma unroll
    for (int m = 0; m < 32; ++m)
        sji = fmaf(fmaxf(acc[m], 0.f), W3[m], sji);

    float val = (sij - sji) * mask[(size_t)bi * NATOM + j];

    // ---- reduction over j per row ----
    sVal[r][j] = val;
    __syncthreads();
    if (tid < 256) {
        int rr = tid >> 6;            // wave id == row (64 threads/wave)
        int l  = tid & 63;
        float s = sVal[rr][l] + (l < 32 ? sVal[rr][64 + l] : 0.f);
#pragma unroll
        for (int off = 32; off > 0; off >>= 1) s += __shfl_xor(s, off);
        if (l == 0) qout[bi0 + rr] = qin[bi0 + rr] + s;
    }
}

// ---------------------------------------------------------------------------
extern "C" void kernel_launch(void* const* d_in, const int* in_sizes, int n_in,
                              void* d_out, int out_size, void* d_ws, size_t ws_size,
                              hipStream_t stream) {
    const float* h    = (const float*)d_in[0];
    const float* e    = (const float*)d_in[1];
    const float* q    = (const float*)d_in[2];
    const float* mask = (const float*)d_in[3];
    const float* W1   = (const float*)d_in[4];
    const float* b1   = (const float*)d_in[5];
    const float* W2   = (const float*)d_in[6];
    const float* b2   = (const float*)d_in[7];
    const float* W3   = (const float*)d_in[8];
    // d_in[9] = b3: cancels exactly in (elec_ij - elec_ji); unused.

    float* u = (float*)d_ws;               // BN*32 floats
    float* v = u + BN * 32;                // BN*32 floats
    float* qout = (float*)d_out;           // BN floats

    uv_kernel<<<(BN * 32 + 255) / 256, 256, 0, stream>>>(h, q, W1, b1, u, v);
    edge_kernel<<<BN / 4, 384, 0, stream>>>(e, mask, q, W1, W2, b2, W3, u, v, qout);
}